// Round 4
// baseline (524.893 us; speedup 1.0000x reference)
//
#include <hip/hip_runtime.h>
#include <math.h>

// Problem dims (fixed by reference)
#define Bsz 64
#define Ssz 512
#define Hsz 400
#define Dsz 400
#define Vsz 32000
#define Lsz 16
#define H3  1200   // 3*H

// Workspace layout (float offsets)
#define WT_HH_OFF 0                 // 400*1200 transposed W_hh [k][j]  (fallback only)
#define WT_IH_OFF 480000            // 400*1200 transposed W_ih [k][j]  (fallback only)
#define HQ_OFF    960000            // 16 bg * 2(ping/pong) * 1600 floats  h buffers
#define GI_OFF    1011200           // 16*1200*64   gi[t][j][b]
#define HALL_OFF  2240000           // 64*16*400    h_all[b][t][d]
#define SCALL_OFF 2649600           // 16*64*512    scores[t][b][s]
#define CTR_OFF   3173888           // 16 barrier counters, stride 32 uints (512 uints)
// total 3,174,400 floats = 12.7 MB

#define NBG   16                    // batch groups (4 batches each)
#define DGRP  16                    // d-groups = blocks per batch-group barrier
#define NBLK_CHAIN 256              // NBG * DGRP; 1 block/CU -> co-resident
#define PROBS4 8192000              // B*L*V/4 float4
#define START4 8192256              // (B*L*V + B*L)/4 : tail after preds region

// part index: [ks][gate][dd][bq]
#define PIDX(ks, g, dd, bq) ((((ks) * 3 + (g)) * 25 + (dd)) * 4 + (bq))

// native vector type for nontemporal builtins (HIP float4 class is rejected)
typedef float nf4 __attribute__((ext_vector_type(4)));

// ---------------------------------------------------------------------------
// k_init: tf==1: h0 + barrier ctrs (+tail zero). tf==0: full zero + WT + h0.
// ---------------------------------------------------------------------------
__global__ __launch_bounds__(256) void k_init(const float* __restrict__ W_hh,
                                              const float* __restrict__ W_ih,
                                              const float* __restrict__ enc_hidden,
                                              const int* __restrict__ tf_p,
                                              float4* __restrict__ out4, int n4,
                                              float* __restrict__ ws) {
    const int tf = tf_p[0];
    const int z0 = tf ? START4 : 0;          // first out4 index to zero
    const int nz = (n4 > z0) ? (n4 - z0) : 0;
    const int nT = tf ? 0 : 480000;          // transpose regions only for fallback
    const int R1 = nz + nT;
    const int R2 = R1 + nT;
    const int R3 = R2 + 25600;
    const int R4 = R3 + 512;
    int stride = gridDim.x * 256;
    for (int i = blockIdx.x * 256 + threadIdx.x; i < R4; i += stride) {
        if (i < nz) {
            out4[z0 + i] = make_float4(0.f, 0.f, 0.f, 0.f);
        } else if (i < R1) {
            int r = i - nz;
            int k = r / 1200, j = r % 1200;
            ws[WT_HH_OFF + r] = W_hh[(size_t)j * Hsz + k];
        } else if (i < R2) {
            int r = i - R1;
            int k = r / 1200, j = r % 1200;
            ws[WT_IH_OFF + r] = W_ih[(size_t)j * Dsz + k];
        } else if (i < R3) {
            int r = i - R2;
            int k = r >> 6, B = r & 63;
            // per-bg ping buffer, layout float4[k4][b] within group
            ws[HQ_OFF + (B >> 2) * 3200 + (((k >> 2) << 2) + (B & 3)) * 4 + (k & 3)]
                = enc_hidden[B * Hsz + k];
        } else {
            ((unsigned*)(ws + CTR_OFF))[i - R3] = 0u;
        }
    }
}

// ---------------------------------------------------------------------------
// k_gi (tf==1 only): gi[t][j][b] = (x_t[b] @ W_ih^T)[j], tiled GEMM.
// ---------------------------------------------------------------------------
__global__ __launch_bounds__(256) void k_gi(const int* __restrict__ tgt,
                                            const int* __restrict__ slot_p,
                                            const int* __restrict__ tf_p,
                                            const float* __restrict__ embedding,
                                            const float* __restrict__ slot_emb,
                                            const float* __restrict__ W_ih,
                                            float* __restrict__ gi) {
    if (tf_p[0] == 0) return;
    __shared__ float4 xs[100 * 64];   // 102.4 KB, [k4][b]

    int t  = blockIdx.x >> 4;
    int jc = blockIdx.x & 15;
    int tid = threadIdx.x;
    int lane = tid & 63, wv = tid >> 6;

    {
        int bb = tid & 63, q = tid >> 6;
        const float* src = (t == 0)
            ? (slot_emb + (size_t)slot_p[0] * Dsz)
            : (embedding + (size_t)tgt[bb * Lsz + (t - 1)] * Dsz);
        const float4* src4 = (const float4*)src;
        for (int k4 = q * 25; k4 < q * 25 + 25; ++k4) xs[k4 * 64 + bb] = src4[k4];
    }
    __syncthreads();

    for (int g = wv; g < 19; g += 4) {
        int j0l = g * 4;
        int nj = (j0l + 4 <= 75) ? 4 : (75 - j0l);
        int j0 = jc * 75 + j0l;
        const float4* w0 = (const float4*)(W_ih + (size_t)(j0 + 0) * Dsz);
        const float4* w1 = (const float4*)(W_ih + (size_t)(j0 + ((nj > 1) ? 1 : 0)) * Dsz);
        const float4* w2 = (const float4*)(W_ih + (size_t)(j0 + ((nj > 2) ? 2 : 0)) * Dsz);
        const float4* w3 = (const float4*)(W_ih + (size_t)(j0 + ((nj > 3) ? 3 : 0)) * Dsz);
        float a0 = 0.f, a1 = 0.f, a2 = 0.f, a3 = 0.f;
        for (int k4 = 0; k4 < 100; ++k4) {
            float4 xv = xs[k4 * 64 + lane];
            float4 r0 = w0[k4], r1 = w1[k4], r2 = w2[k4], r3 = w3[k4];
            a0 = fmaf(r0.x, xv.x, a0); a0 = fmaf(r0.y, xv.y, a0);
            a0 = fmaf(r0.z, xv.z, a0); a0 = fmaf(r0.w, xv.w, a0);
            a1 = fmaf(r1.x, xv.x, a1); a1 = fmaf(r1.y, xv.y, a1);
            a1 = fmaf(r1.z, xv.z, a1); a1 = fmaf(r1.w, xv.w, a1);
            a2 = fmaf(r2.x, xv.x, a2); a2 = fmaf(r2.y, xv.y, a2);
            a2 = fmaf(r2.z, xv.z, a2); a2 = fmaf(r2.w, xv.w, a2);
            a3 = fmaf(r3.x, xv.x, a3); a3 = fmaf(r3.y, xv.y, a3);
            a3 = fmaf(r3.z, xv.z, a3); a3 = fmaf(r3.w, xv.w, a3);
        }
        float* go = gi + ((size_t)t * H3 + j0) * 64 + lane;
        go[0] = a0;
        if (nj > 1) go[64] = a1;
        if (nj > 2) go[128] = a2;
        if (nj > 3) go[192] = a3;
    }
}

// ---------------------------------------------------------------------------
// k_chain: tf==1: 256 blocks = 16 batch-groups (4 b each) x 16 d-groups
// (25 d each). Per-bg 16-block barrier (2 release-adds per block, one per
// finalize wave); h exchanged via 6.4 KB cache-bypass buffers.
// GEMV mapping: (ks, dd, bq) = 300 threads, 3 gate-rows per thread ->
// 4 LDS reads per 12 FMA (was 2 per 4), 2-way-free bank geometry.
// tf==0: blocks 0..63 run independent per-batch full decode (unchanged).
// ---------------------------------------------------------------------------
struct SmemChain {
    float4 W4[75 * 101];    // 121.2 KB  W_hh slice rows (padded to 101 float4)
    float4 h4[400];         //   6.4 KB  h staged [k4][b] for the 4 batches
    float  part[900];       //   3.6 KB  [ks][gate][dd][bq]
};
struct SmemFallback {
    float part_i[3 * H3];
    float part_h[3 * H3];
    float hx[Hsz];
    float xv[Dsz];
    float sL[Ssz];
    float redv[15];
    int   redi[15];
    float bc_max, bc_sum;
    int   bc_idx;
};
union SmemU { SmemChain c; SmemFallback f; };

__device__ __forceinline__ float sigmoidf_(float x) { return 1.f / (1.f + expf(-x)); }

__global__ __launch_bounds__(960) void k_chain(const float* __restrict__ ws_ro,
                                               const float* __restrict__ gi,
                                               const float* __restrict__ W_hh,
                                               const float* __restrict__ enc_hidden,
                                               const float* __restrict__ enc_out,
                                               const int* __restrict__ lens,
                                               const int* __restrict__ uttrs,
                                               const int* __restrict__ slot_p,
                                               const int* __restrict__ tf_p,
                                               const float* __restrict__ embedding,
                                               const float* __restrict__ slot_emb,
                                               const float* __restrict__ b_ih,
                                               const float* __restrict__ b_hh,
                                               float* __restrict__ ws_rw,
                                               float* __restrict__ h_all,
                                               float* __restrict__ out_probs,
                                               float* __restrict__ preds_out) {
    __shared__ SmemU sm;
    const int tid = threadIdx.x;
    const int tf  = tf_p[0];

    if (tf != 0) {
        // ================= grouped h-chain =================
        const int bg = blockIdx.x & 15;      // batch group (4 batches)
        const int dg = blockIdx.x >> 4;      // d group (25 dims)
        const int D0 = dg * 25;
        unsigned* ctr = (unsigned*)(ws_rw + CTR_OFF) + bg * 32;

        // preload W_hh slice: rows r = g*25+dd (g gate, dd local dim), padded LDS
        for (int i = tid; i < 7500; i += 960) {
            int r = i / 100, k4 = i % 100;
            int g = r / 25, dd = r % 25;
            sm.c.W4[r * 101 + k4] =
                ((const float4*)(W_hh + (size_t)(g * Hsz + D0 + dd) * Hsz))[k4];
        }

        // finalize unit: one (dd,bq) per thread, tids 0..99 (waves 0 and 1)
        const bool is_fin = (tid < 100);
        const int  fbq = tid & 3, fdd = tid >> 2;
        const int  fd  = D0 + fdd;
        float g1r = 0.f, g1z = 0.f, g1n = 0.f;   // gi for current step
        float g2r = 0.f, g2z = 0.f, g2n = 0.f;   // gi prefetch for next step
        float bir = 0.f, biz = 0.f, bin = 0.f;
        float bhr = 0.f, bhz = 0.f, bhn = 0.f;
        if (is_fin) {
            bir = b_ih[fd]; biz = b_ih[fd + Hsz]; bin = b_ih[fd + 2 * Hsz];
            bhr = b_hh[fd]; bhz = b_hh[fd + Hsz]; bhn = b_hh[fd + 2 * Hsz];
            const float* gp = gi + (size_t)fd * 64 + (bg * 4 + fbq);
            g1r = gp[0];
            g1z = gp[(size_t)Hsz * 64];
            g1n = gp[(size_t)2 * Hsz * 64];
        }
        __syncthreads();

        for (int t = 0; t < Lsz; ++t) {
            const unsigned long long* hq8 = (const unsigned long long*)
                (ws_ro + HQ_OFF + (size_t)(bg * 2 + (t & 1)) * 1600);
            float* hq_nxt = ws_rw + HQ_OFF + (size_t)(bg * 2 + ((t & 1) ^ 1)) * 1600;

            // stage h via cache-bypassing loads (fresh from IF, no inv needed)
            unsigned long long* h8 = (unsigned long long*)sm.c.h4;
            if (tid < 800)
                h8[tid] = __hip_atomic_load(hq8 + tid, __ATOMIC_RELAXED,
                                            __HIP_MEMORY_SCOPE_AGENT);
            __syncthreads();

            // gi(t+1) prefetch issued early: L2 latency hides under the GEMV
            if (is_fin && t + 1 < Lsz) {
                const float* gp = gi + ((size_t)(t + 1) * H3 + fd) * 64
                                + (bg * 4 + fbq);
                g2r = gp[0];
                g2z = gp[(size_t)Hsz * 64];
                g2n = gp[(size_t)2 * Hsz * 64];
            }

            // GEMV partials: thread = (ks, dd, bq); 3 gate-rows per thread.
            // Per k4: 1 h-read (broadcast) + 3 W-reads (2-way free) -> 12 FMA.
            if (tid < 300) {
                int ks  = tid / 100;
                int idx = tid % 100;
                int bq  = idx & 3;
                int dd  = idx >> 2;
                int k4b = (ks == 0) ? 0 : (ks == 1) ? 34 : 67;
                int k4e = (ks == 0) ? 34 : (ks == 1) ? 67 : 100;
                const float4* Wr = sm.c.W4 + (0 * 25 + dd) * 101;
                const float4* Wz = sm.c.W4 + (1 * 25 + dd) * 101;
                const float4* Wn = sm.c.W4 + (2 * 25 + dd) * 101;
                float4 ar = make_float4(0.f, 0.f, 0.f, 0.f);
                float4 az = make_float4(0.f, 0.f, 0.f, 0.f);
                float4 an = make_float4(0.f, 0.f, 0.f, 0.f);
                for (int k4 = k4b; k4 < k4e; ++k4) {
                    float4 hv = sm.c.h4[(k4 << 2) | bq];
                    float4 wr = Wr[k4], wz = Wz[k4], wn = Wn[k4];
                    ar.x = fmaf(wr.x, hv.x, ar.x); ar.y = fmaf(wr.y, hv.y, ar.y);
                    ar.z = fmaf(wr.z, hv.z, ar.z); ar.w = fmaf(wr.w, hv.w, ar.w);
                    az.x = fmaf(wz.x, hv.x, az.x); az.y = fmaf(wz.y, hv.y, az.y);
                    az.z = fmaf(wz.z, hv.z, az.z); az.w = fmaf(wz.w, hv.w, az.w);
                    an.x = fmaf(wn.x, hv.x, an.x); an.y = fmaf(wn.y, hv.y, an.y);
                    an.z = fmaf(wn.z, hv.z, an.z); an.w = fmaf(wn.w, hv.w, an.w);
                }
                sm.c.part[PIDX(ks, 0, dd, bq)] = (ar.x + ar.y) + (ar.z + ar.w);
                sm.c.part[PIDX(ks, 1, dd, bq)] = (az.x + az.y) + (az.z + az.w);
                sm.c.part[PIDX(ks, 2, dd, bq)] = (an.x + an.y) + (an.z + an.w);
            }
            __syncthreads();

            // finalize: waves 0+1, one unit per thread
            if (is_fin) {
                float ghr = sm.c.part[PIDX(0, 0, fdd, fbq)]
                          + sm.c.part[PIDX(1, 0, fdd, fbq)]
                          + sm.c.part[PIDX(2, 0, fdd, fbq)] + bhr;
                float ghz = sm.c.part[PIDX(0, 1, fdd, fbq)]
                          + sm.c.part[PIDX(1, 1, fdd, fbq)]
                          + sm.c.part[PIDX(2, 1, fdd, fbq)] + bhz;
                float ghn = sm.c.part[PIDX(0, 2, fdd, fbq)]
                          + sm.c.part[PIDX(1, 2, fdd, fbq)]
                          + sm.c.part[PIDX(2, 2, fdd, fbq)] + bhn;
                float rr = sigmoidf_(g1r + bir + ghr);
                float zz = sigmoidf_(g1z + biz + ghz);
                float nn = tanhf(g1n + bin + rr * ghn);
                int hidx = (((fd >> 2) << 2) | fbq) * 4 + (fd & 3);
                float hp = ((const float*)sm.c.h4)[hidx];
                float hv = (1.f - zz) * nn + zz * hp;
                // device-visible (IF) store: peers read via bypass loads
                __hip_atomic_store(&hq_nxt[hidx], hv, __ATOMIC_RELAXED,
                                   __HIP_MEMORY_SCOPE_AGENT);
                h_all[(size_t)(bg * 4 + fbq) * (Lsz * Hsz)
                      + (size_t)t * Hsz + fd] = hv;
                g1r = g2r; g1z = g2z; g1n = g2n;
            }

            if (t < Lsz - 1) {
                __syncthreads();
                // one release-add per finalize wave: each wave's release drains
                // its OWN h stores (vmcnt is per-wave) before publishing at IF
                if (tid == 0 || tid == 64) {
                    __hip_atomic_fetch_add(ctr, 1u, __ATOMIC_RELEASE,
                                           __HIP_MEMORY_SCOPE_AGENT);
                }
                if (tid == 0) {
                    unsigned target = 2u * (unsigned)DGRP * (t + 1);
                    while (__hip_atomic_load(ctr, __ATOMIC_RELAXED,
                                             __HIP_MEMORY_SCOPE_AGENT) < target) {
                        __builtin_amdgcn_s_sleep(1);
                    }
                }
                __syncthreads();
            }
        }
        return;
    }

    // ================= tf==0 fallback: per-batch independent decode =========
    if (blockIdx.x >= Bsz) return;
    const int b    = blockIdx.x;
    const int lane = tid & 63;
    const int w    = tid >> 6;          // 0..14
    const int jc   = tid % 300;
    const int ksf  = tid / 300;
    const int kbeg = ksf * 134;
    const int kend = (ksf == 2) ? Hsz : kbeg + 134;
    const int len  = lens[b];

    const float4* WTH4 = (const float4*)(ws_ro + WT_HH_OFF);
    const float4* WTI4 = (const float4*)(ws_ro + WT_IH_OFF);

    if (tid < Hsz) {
        sm.f.hx[tid] = enc_hidden[b * Hsz + tid];
        sm.f.xv[tid] = slot_emb[(size_t)slot_p[0] * Dsz + tid];
    }
    __syncthreads();

    for (int t = 0; t < Lsz; ++t) {
        if (tid < 900) {
            float4 ai = make_float4(0.f, 0.f, 0.f, 0.f);
            float4 ah = make_float4(0.f, 0.f, 0.f, 0.f);
            for (int k = kbeg; k < kend; ++k) {
                float4 wi = WTI4[(size_t)k * 300 + jc];
                float4 wh = WTH4[(size_t)k * 300 + jc];
                float x = sm.f.xv[k], h = sm.f.hx[k];
                ai.x = fmaf(wi.x, x, ai.x); ai.y = fmaf(wi.y, x, ai.y);
                ai.z = fmaf(wi.z, x, ai.z); ai.w = fmaf(wi.w, x, ai.w);
                ah.x = fmaf(wh.x, h, ah.x); ah.y = fmaf(wh.y, h, ah.y);
                ah.z = fmaf(wh.z, h, ah.z); ah.w = fmaf(wh.w, h, ah.w);
            }
            ((float4*)sm.f.part_i)[ksf * 300 + jc] = ai;
            ((float4*)sm.f.part_h)[ksf * 300 + jc] = ah;
        }
        __syncthreads();

        if (tid < Hsz) {
            int d = tid;
            float i_r = sm.f.part_i[d]           + sm.f.part_i[H3 + d]           + sm.f.part_i[2 * H3 + d]           + b_ih[d];
            float i_z = sm.f.part_i[d + Hsz]     + sm.f.part_i[H3 + d + Hsz]     + sm.f.part_i[2 * H3 + d + Hsz]     + b_ih[d + Hsz];
            float i_n = sm.f.part_i[d + 2 * Hsz] + sm.f.part_i[H3 + d + 2 * Hsz] + sm.f.part_i[2 * H3 + d + 2 * Hsz] + b_ih[d + 2 * Hsz];
            float h_r = sm.f.part_h[d]           + sm.f.part_h[H3 + d]           + sm.f.part_h[2 * H3 + d]           + b_hh[d];
            float h_z = sm.f.part_h[d + Hsz]     + sm.f.part_h[H3 + d + Hsz]     + sm.f.part_h[2 * H3 + d + Hsz]     + b_hh[d + Hsz];
            float h_n = sm.f.part_h[d + 2 * Hsz] + sm.f.part_h[H3 + d + 2 * Hsz] + sm.f.part_h[2 * H3 + d + 2 * Hsz] + b_hh[d + 2 * Hsz];
            float r = sigmoidf_(i_r + h_r);
            float z = sigmoidf_(i_z + h_z);
            float n = tanhf(i_n + r * h_n);
            sm.f.hx[d] = (1.f - z) * n + z * sm.f.hx[d];
        }
        __syncthreads();

        const float4* hx4 = (const float4*)sm.f.hx;
        for (int s = w; s < len; s += 15) {
            const float4* e4 = (const float4*)(enc_out + ((size_t)b * Ssz + s) * Hsz);
            float4 ev = e4[lane];
            float4 hv = hx4[lane];
            float acc = ev.x * hv.x + ev.y * hv.y + ev.z * hv.z + ev.w * hv.w;
            if (lane < 36) {
                float4 ev2 = e4[64 + lane];
                float4 hv2 = hx4[64 + lane];
                acc += ev2.x * hv2.x + ev2.y * hv2.y + ev2.z * hv2.z + ev2.w * hv2.w;
            }
            #pragma unroll
            for (int off = 32; off >= 1; off >>= 1) acc += __shfl_xor(acc, off, 64);
            if (lane == 0) sm.f.sL[s] = acc;
        }
        __syncthreads();

        float bv = -INFINITY; int bi = 0x7fffffff;
        for (int s = tid; s < len; s += 960) {
            float v = sm.f.sL[s];
            if (v > bv || (v == bv && s < bi)) { bv = v; bi = s; }
        }
        #pragma unroll
        for (int off = 32; off >= 1; off >>= 1) {
            float ov = __shfl_xor(bv, off, 64);
            int   oi = __shfl_xor(bi, off, 64);
            if (ov > bv || (ov == bv && oi < bi)) { bv = ov; bi = oi; }
        }
        if (lane == 0) { sm.f.redv[w] = bv; sm.f.redi[w] = bi; }
        __syncthreads();
        if (tid == 0) {
            float mv = sm.f.redv[0]; int mi = sm.f.redi[0];
            for (int i = 1; i < 15; ++i)
                if (sm.f.redv[i] > mv || (sm.f.redv[i] == mv && sm.f.redi[i] < mi)) {
                    mv = sm.f.redv[i]; mi = sm.f.redi[i];
                }
            sm.f.bc_max = mv; sm.f.bc_idx = mi;
        }
        __syncthreads();
        float maxv = sm.f.bc_max;
        int   amax = sm.f.bc_idx;

        float ls = 0.f;
        for (int s = tid; s < len; s += 960) {
            float e = expf(sm.f.sL[s] - maxv);
            sm.f.sL[s] = e;
            ls += e;
        }
        #pragma unroll
        for (int off = 32; off >= 1; off >>= 1) ls += __shfl_xor(ls, off, 64);
        if (lane == 0) sm.f.redv[w] = ls;
        __syncthreads();
        if (tid == 0) {
            float sms = 0.f;
            for (int i = 0; i < 15; ++i) sms += sm.f.redv[i];
            sm.f.bc_sum = sms;
        }
        __syncthreads();
        float sum = sm.f.bc_sum;

        float* orow = out_probs + (size_t)b * (Lsz * Vsz) + (size_t)t * Vsz;
        for (int s = tid; s < len; s += 960) {
            atomicAdd(&orow[uttrs[b * Ssz + s]], sm.f.sL[s] / sum);
        }

        int predtok = uttrs[b * Ssz + amax];
        if (tid == 0) preds_out[(size_t)t * Bsz + b] = (float)predtok;
        __syncthreads();
        if (tid < Dsz) sm.f.xv[tid] = embedding[(size_t)predtok * Dsz + tid];
        __syncthreads();
    }
}

// ---------------------------------------------------------------------------
// Batched scores (tf==1): scores[t][b][s] = h_t[b].enc_out[b][s], s < len[b].
// ---------------------------------------------------------------------------
__global__ __launch_bounds__(256) void k_scores(const float* __restrict__ h_all,
                                                const float* __restrict__ enc_out,
                                                const int* __restrict__ lens,
                                                const int* __restrict__ tf_p,
                                                float* __restrict__ scores_all) {
    if (tf_p[0] == 0) return;
    __shared__ float4 hS[Lsz * 100];   // 25.6 KB

    int b  = blockIdx.x >> 3;
    int sc = blockIdx.x & 7;
    int tid = threadIdx.x;
    int lane = tid & 63;
    int w = tid >> 6;

    const float4* h4g = (const float4*)(h_all + (size_t)b * (Lsz * Hsz));
    for (int i = tid; i < Lsz * 100; i += 256) hS[i] = h4g[i];
    __syncthreads();

    int len = lens[b];
    int l2 = 64 + ((lane < 36) ? lane : 0);
    float mult2 = (lane < 36) ? 1.f : 0.f;

    for (int i = 0; i < 16; ++i) {
        int s = sc * 64 + i * 4 + w;
        if (s >= len) continue;
        const float4* e4 = (const float4*)(enc_out + ((size_t)b * Ssz + s) * Hsz);
        float4 ev  = e4[lane];
        float4 ev2 = e4[l2];
        ev2.x *= mult2; ev2.y *= mult2; ev2.z *= mult2; ev2.w *= mult2;

        float acc[Lsz];
        #pragma unroll
        for (int t = 0; t < Lsz; ++t) {
            float4 hv  = hS[t * 100 + lane];
            float4 hv2 = hS[t * 100 + l2];
            float a = ev.x * hv.x + ev.y * hv.y + ev.z * hv.z + ev.w * hv.w;
            a += ev2.x * hv2.x + ev2.y * hv2.y + ev2.z * hv2.z + ev2.w * hv2.w;
            acc[t] = a;
        }
        #pragma unroll
        for (int off = 32; off >= 1; off >>= 1) {
            #pragma unroll
            for (int t = 0; t < Lsz; ++t) acc[t] += __shfl_xor(acc[t], off, 64);
        }
        if (lane == 0) {
            #pragma unroll
            for (int t = 0; t < Lsz; ++t)
                scores_all[(size_t)t * (Bsz * Ssz) + b * Ssz + s] = acc[t];
        }
    }
}

// ---------------------------------------------------------------------------
// Batched softmax + LDS-vocab scatter + argmax (tf==1): one block per (t,b).
// Accumulates pointer dist in 128 KB LDS, streams full row out (no zeroing,
// no global atomics).
// ---------------------------------------------------------------------------
__global__ __launch_bounds__(256) void k_softmax_all(const float* __restrict__ scores_all,
                                                     const int* __restrict__ lens,
                                                     const int* __restrict__ uttrs,
                                                     const int* __restrict__ tf_p,
                                                     float* __restrict__ out_probs,
                                                     float* __restrict__ preds_out) {
    if (tf_p[0] == 0) return;
    __shared__ float4 vb4[Vsz / 4];   // 128 KB vocab accumulator
    __shared__ float sL[Ssz];
    __shared__ float redv[4];
    __shared__ int   redi[4];
    __shared__ float bc_max, bc_sum;
    __shared__ int   bc_idx;

    int t = blockIdx.x >> 6;
    int b = blockIdx.x & 63;
    int tid = threadIdx.x;
    int lane = tid & 63, w = tid >> 6;
    int len = lens[b];
    const float* srow = scores_all + (size_t)t * (Bsz * Ssz) + b * Ssz;

    float4 z4 = make_float4(0.f, 0.f, 0.f, 0.f);
    for (int i = tid; i < Vsz / 4; i += 256) vb4[i] = z4;

    for (int s = tid; s < len; s += 256) sL[s] = srow[s];
    __syncthreads();

    float bv = -INFINITY; int bi = 0x7fffffff;
    for (int s = tid; s < len; s += 256) {
        float v = sL[s];
        if (v > bv || (v == bv && s < bi)) { bv = v; bi = s; }
    }
    #pragma unroll
    for (int off = 32; off >= 1; off >>= 1) {
        float ov = __shfl_xor(bv, off, 64);
        int   oi = __shfl_xor(bi, off, 64);
        if (ov > bv || (ov == bv && oi < bi)) { bv = ov; bi = oi; }
    }
    if (lane == 0) { redv[w] = bv; redi[w] = bi; }
    __syncthreads();
    if (tid == 0) {
        float mv = redv[0]; int mi = redi[0];
        for (int i = 1; i < 4; ++i)
            if (redv[i] > mv || (redv[i] == mv && redi[i] < mi)) { mv = redv[i]; mi = redi[i]; }
        bc_max = mv; bc_idx = mi;
    }
    __syncthreads();
    float maxv = bc_max;
    int   amax = bc_idx;

    float ls = 0.f;
    for (int s = tid; s < len; s += 256) {
        float e = expf(sL[s] - maxv);
        sL[s] = e;
        ls += e;
    }
    #pragma unroll
    for (int off = 32; off >= 1; off >>= 1) ls += __shfl_xor(ls, off, 64);
    if (lane == 0) redv[w] = ls;
    __syncthreads();
    if (tid == 0) bc_sum = redv[0] + redv[1] + redv[2] + redv[3];
    __syncthreads();
    float sum = bc_sum;

    float* vbf = (float*)vb4;
    for (int s = tid; s < len; s += 256) {
        atomicAdd(&vbf[uttrs[b * Ssz + s]], sL[s] / sum);
    }
    __syncthreads();

    // stream the full vocab row out nontemporally (native vector type)
    const nf4* vbn = (const nf4*)vb4;
    nf4* orow4 = (nf4*)(out_probs + (size_t)b * (Lsz * Vsz) + (size_t)t * Vsz);
    for (int i = tid; i < Vsz / 4; i += 256)
        __builtin_nontemporal_store(vbn[i], &orow4[i]);

    if (tid == 0) preds_out[(size_t)t * Bsz + b] = (float)uttrs[b * Ssz + amax];
}

// ---------------------------------------------------------------------------
extern "C" void kernel_launch(void* const* d_in, const int* in_sizes, int n_in,
                              void* d_out, int out_size, void* d_ws, size_t ws_size,
                              hipStream_t stream) {
    const float* enc_hidden = (const float*)d_in[0];
    const float* enc_out    = (const float*)d_in[1];
    const int*   enc_lens   = (const int*)d_in[2];
    const int*   uttrs      = (const int*)d_in[3];
    const int*   tgt        = (const int*)d_in[4];
    const int*   slot_p     = (const int*)d_in[5];
    const int*   tf_p       = (const int*)d_in[6];
    const float* embedding  = (const float*)d_in[7];
    const float* slot_emb   = (const float*)d_in[8];
    const float* W_ih       = (const float*)d_in[9];
    const float* W_hh       = (const float*)d_in[10];
    const float* b_ih       = (const float*)d_in[11];
    const float* b_hh       = (const float*)d_in[12];

    float* out = (float*)d_out;
    float* ws  = (float*)d_ws;

    float* gi_all     = ws + GI_OFF;
    float* h_all      = ws + HALL_OFF;
    float* scores_all = ws + SCALL_OFF;
    float* preds_out  = out + (size_t)Bsz * Lsz * Vsz;

    int n4 = out_size >> 2;

    // 1) init: h0 + barrier ctrs (+ full zero / WT transposes only if tf==0)
    k_init<<<2048, 256, 0, stream>>>(W_hh, W_ih, enc_hidden, tf_p,
                                     (float4*)d_out, n4, ws);

    // 2) gi GEMM for all 16 steps (tf==1 only)
    k_gi<<<256, 256, 0, stream>>>(tgt, slot_p, tf_p, embedding, slot_emb,
                                  W_ih, gi_all);

    // 3) chain (tf==1: 16 independent group-barriers; tf==0: per-batch fallback)
    k_chain<<<NBLK_CHAIN, 960, 0, stream>>>(ws, gi_all, W_hh, enc_hidden, enc_out,
                                            enc_lens, uttrs, slot_p, tf_p,
                                            embedding, slot_emb, b_ih, b_hh,
                                            ws, h_all, out, preds_out);

    // 4) batched scores + softmax/scatter (tf==1 only)
    k_scores<<<512, 256, 0, stream>>>(h_all, enc_out, enc_lens, tf_p, scores_all);
    k_softmax_all<<<1024, 256, 0, stream>>>(scores_all, enc_lens, uttrs, tf_p,
                                            out, preds_out);
}

// Round 5
// 480.614 us; speedup vs baseline: 1.0921x; 1.0921x over previous
//
#include <hip/hip_runtime.h>
#include <math.h>

// Problem dims (fixed by reference)
#define Bsz 64
#define Ssz 512
#define Hsz 400
#define Dsz 400
#define Vsz 32000
#define Lsz 16
#define H3  1200   // 3*H

// Workspace layout (float offsets)
#define WT_HH_OFF 0                 // 400*1200 transposed W_hh [k][j]  (fallback only)
#define WT_IH_OFF 480000            // 400*1200 transposed W_ih [k][j]  (fallback only)
#define HQ_OFF    960000            // 16 bg * 2(ping/pong) * 1600 floats  h buffers
#define GI_OFF    1011200           // 16*1200*64   gi[t][j][b]
#define HALL_OFF  2240000           // 64*16*400    h_all[b][t][d]
#define SCALL_OFF 2649600           // 16*64*512    scores[t][b][s]
#define CTR_OFF   3173888           // 16 barrier counters, stride 32 uints (512 uints)
// total 3,174,400 floats = 12.7 MB

#define NBG   16                    // batch groups (4 batches each)
#define DGRP  16                    // d-groups = blocks per batch-group barrier
#define NBLK_CHAIN 256              // NBG * DGRP; 1 block/CU -> co-resident
#define KS    18                    // k-splits in the chain GEMV
#define PROBS4 8192000              // B*L*V/4 float4
#define START4 8192256              // (B*L*V + B*L)/4 : tail after preds region

// part index: [ks][gate][dd][bq]
#define PIDX(ks, g, dd, bq) ((((ks) * 3 + (g)) * 25 + (dd)) * 4 + (bq))

// native vector type for nontemporal builtins (HIP float4 class is rejected)
typedef float nf4 __attribute__((ext_vector_type(4)));

// ---------------------------------------------------------------------------
// k_init: tf==1: h0 + barrier ctrs (+tail zero). tf==0: full zero + WT + h0.
// ---------------------------------------------------------------------------
__global__ __launch_bounds__(256) void k_init(const float* __restrict__ W_hh,
                                              const float* __restrict__ W_ih,
                                              const float* __restrict__ enc_hidden,
                                              const int* __restrict__ tf_p,
                                              float4* __restrict__ out4, int n4,
                                              float* __restrict__ ws) {
    const int tf = tf_p[0];
    const int z0 = tf ? START4 : 0;          // first out4 index to zero
    const int nz = (n4 > z0) ? (n4 - z0) : 0;
    const int nT = tf ? 0 : 480000;          // transpose regions only for fallback
    const int R1 = nz + nT;
    const int R2 = R1 + nT;
    const int R3 = R2 + 25600;
    const int R4 = R3 + 512;
    int stride = gridDim.x * 256;
    for (int i = blockIdx.x * 256 + threadIdx.x; i < R4; i += stride) {
        if (i < nz) {
            out4[z0 + i] = make_float4(0.f, 0.f, 0.f, 0.f);
        } else if (i < R1) {
            int r = i - nz;
            int k = r / 1200, j = r % 1200;
            ws[WT_HH_OFF + r] = W_hh[(size_t)j * Hsz + k];
        } else if (i < R2) {
            int r = i - R1;
            int k = r / 1200, j = r % 1200;
            ws[WT_IH_OFF + r] = W_ih[(size_t)j * Dsz + k];
        } else if (i < R3) {
            int r = i - R2;
            int k = r >> 6, B = r & 63;
            // per-bg ping buffer, layout float4[k4][b] within group
            ws[HQ_OFF + (B >> 2) * 3200 + (((k >> 2) << 2) + (B & 3)) * 4 + (k & 3)]
                = enc_hidden[B * Hsz + k];
        } else {
            ((unsigned*)(ws + CTR_OFF))[i - R3] = 0u;
        }
    }
}

// ---------------------------------------------------------------------------
// k_gi (tf==1 only): gi[t][j][b] = (x_t[b] @ W_ih^T)[j], tiled GEMM.
// ---------------------------------------------------------------------------
__global__ __launch_bounds__(256) void k_gi(const int* __restrict__ tgt,
                                            const int* __restrict__ slot_p,
                                            const int* __restrict__ tf_p,
                                            const float* __restrict__ embedding,
                                            const float* __restrict__ slot_emb,
                                            const float* __restrict__ W_ih,
                                            float* __restrict__ gi) {
    if (tf_p[0] == 0) return;
    __shared__ float4 xs[100 * 64];   // 102.4 KB, [k4][b]

    int t  = blockIdx.x >> 4;
    int jc = blockIdx.x & 15;
    int tid = threadIdx.x;
    int lane = tid & 63, wv = tid >> 6;

    {
        int bb = tid & 63, q = tid >> 6;
        const float* src = (t == 0)
            ? (slot_emb + (size_t)slot_p[0] * Dsz)
            : (embedding + (size_t)tgt[bb * Lsz + (t - 1)] * Dsz);
        const float4* src4 = (const float4*)src;
        for (int k4 = q * 25; k4 < q * 25 + 25; ++k4) xs[k4 * 64 + bb] = src4[k4];
    }
    __syncthreads();

    for (int g = wv; g < 19; g += 4) {
        int j0l = g * 4;
        int nj = (j0l + 4 <= 75) ? 4 : (75 - j0l);
        int j0 = jc * 75 + j0l;
        const float4* w0 = (const float4*)(W_ih + (size_t)(j0 + 0) * Dsz);
        const float4* w1 = (const float4*)(W_ih + (size_t)(j0 + ((nj > 1) ? 1 : 0)) * Dsz);
        const float4* w2 = (const float4*)(W_ih + (size_t)(j0 + ((nj > 2) ? 2 : 0)) * Dsz);
        const float4* w3 = (const float4*)(W_ih + (size_t)(j0 + ((nj > 3) ? 3 : 0)) * Dsz);
        float a0 = 0.f, a1 = 0.f, a2 = 0.f, a3 = 0.f;
        for (int k4 = 0; k4 < 100; ++k4) {
            float4 xv = xs[k4 * 64 + lane];
            float4 r0 = w0[k4], r1 = w1[k4], r2 = w2[k4], r3 = w3[k4];
            a0 = fmaf(r0.x, xv.x, a0); a0 = fmaf(r0.y, xv.y, a0);
            a0 = fmaf(r0.z, xv.z, a0); a0 = fmaf(r0.w, xv.w, a0);
            a1 = fmaf(r1.x, xv.x, a1); a1 = fmaf(r1.y, xv.y, a1);
            a1 = fmaf(r1.z, xv.z, a1); a1 = fmaf(r1.w, xv.w, a1);
            a2 = fmaf(r2.x, xv.x, a2); a2 = fmaf(r2.y, xv.y, a2);
            a2 = fmaf(r2.z, xv.z, a2); a2 = fmaf(r2.w, xv.w, a2);
            a3 = fmaf(r3.x, xv.x, a3); a3 = fmaf(r3.y, xv.y, a3);
            a3 = fmaf(r3.z, xv.z, a3); a3 = fmaf(r3.w, xv.w, a3);
        }
        float* go = gi + ((size_t)t * H3 + j0) * 64 + lane;
        go[0] = a0;
        if (nj > 1) go[64] = a1;
        if (nj > 2) go[128] = a2;
        if (nj > 3) go[192] = a3;
    }
}

// ---------------------------------------------------------------------------
// k_chain: tf==1: 256 blocks = 16 batch-groups (4 b each) x 16 d-groups
// (25 d each). Per-bg 16-block barrier; h via 6.4 KB cache-bypass buffers.
// GEMV mapping: (ks 18, dd 25, bp 2) = 900 threads / 14 waves. Each thread:
// 3 gate-rows x 2 batches over ~5.6 k4 -> 5 LDS reads per 24 FMA.
// (R4 lesson: 300-thread version was latency-bound at 1.2 waves/SIMD.)
// tf==0: blocks 0..63 run independent per-batch full decode (unchanged).
// ---------------------------------------------------------------------------
struct SmemChain {
    float4 W4[75 * 101];    // 121.2 KB  W_hh slice rows (padded to 101 float4)
    float4 h4[400];         //   6.4 KB  h staged [k4][b] for the 4 batches
    float  part[KS * 300];  //  21.6 KB  [ks][gate][dd][bq]
};
struct SmemFallback {
    float part_i[3 * H3];
    float part_h[3 * H3];
    float hx[Hsz];
    float xv[Dsz];
    float sL[Ssz];
    float redv[15];
    int   redi[15];
    float bc_max, bc_sum;
    int   bc_idx;
};
union SmemU { SmemChain c; SmemFallback f; };

__device__ __forceinline__ float sigmoidf_(float x) { return 1.f / (1.f + expf(-x)); }

__global__ __launch_bounds__(960) void k_chain(const float* __restrict__ ws_ro,
                                               const float* __restrict__ gi,
                                               const float* __restrict__ W_hh,
                                               const float* __restrict__ enc_hidden,
                                               const float* __restrict__ enc_out,
                                               const int* __restrict__ lens,
                                               const int* __restrict__ uttrs,
                                               const int* __restrict__ slot_p,
                                               const int* __restrict__ tf_p,
                                               const float* __restrict__ embedding,
                                               const float* __restrict__ slot_emb,
                                               const float* __restrict__ b_ih,
                                               const float* __restrict__ b_hh,
                                               float* __restrict__ ws_rw,
                                               float* __restrict__ h_all,
                                               float* __restrict__ out_probs,
                                               float* __restrict__ preds_out) {
    __shared__ SmemU sm;
    const int tid = threadIdx.x;
    const int tf  = tf_p[0];

    if (tf != 0) {
        // ================= grouped h-chain =================
        const int bg = blockIdx.x & 15;      // batch group (4 batches)
        const int dg = blockIdx.x >> 4;      // d group (25 dims)
        const int D0 = dg * 25;
        unsigned* ctr = (unsigned*)(ws_rw + CTR_OFF) + bg * 32;

        // preload W_hh slice: rows r = g*25+dd (g gate, dd local dim), padded LDS
        for (int i = tid; i < 7500; i += 960) {
            int r = i / 100, k4 = i % 100;
            int g = r / 25, dd = r % 25;
            sm.c.W4[r * 101 + k4] =
                ((const float4*)(W_hh + (size_t)(g * Hsz + D0 + dd) * Hsz))[k4];
        }

        // GEMV thread geometry (tid < 900): (ks, dd, bp)
        const int gks = tid / 50;
        const int gidx = tid % 50;
        const int gbp = gidx & 1;
        const int gdd = gidx >> 1;
        const int gk4b = (gks * 100) / KS;
        const int gk4e = ((gks + 1) * 100) / KS;
        const int gbq0 = gbp << 1;

        // finalize unit: one (dd,bq) per thread, tids 0..99 (waves 0 and 1)
        const bool is_fin = (tid < 100);
        const int  fbq = tid & 3, fdd = tid >> 2;
        const int  fd  = D0 + fdd;
        float g1r = 0.f, g1z = 0.f, g1n = 0.f;   // gi for current step
        float g2r = 0.f, g2z = 0.f, g2n = 0.f;   // gi prefetch for next step
        float bir = 0.f, biz = 0.f, bin = 0.f;
        float bhr = 0.f, bhz = 0.f, bhn = 0.f;
        if (is_fin) {
            bir = b_ih[fd]; biz = b_ih[fd + Hsz]; bin = b_ih[fd + 2 * Hsz];
            bhr = b_hh[fd]; bhz = b_hh[fd + Hsz]; bhn = b_hh[fd + 2 * Hsz];
            const float* gp = gi + (size_t)fd * 64 + (bg * 4 + fbq);
            g1r = gp[0];
            g1z = gp[(size_t)Hsz * 64];
            g1n = gp[(size_t)2 * Hsz * 64];
        }
        __syncthreads();

        for (int t = 0; t < Lsz; ++t) {
            const unsigned long long* hq8 = (const unsigned long long*)
                (ws_ro + HQ_OFF + (size_t)(bg * 2 + (t & 1)) * 1600);
            float* hq_nxt = ws_rw + HQ_OFF + (size_t)(bg * 2 + ((t & 1) ^ 1)) * 1600;

            // stage h via cache-bypassing loads (fresh from IF, no inv needed)
            unsigned long long* h8 = (unsigned long long*)sm.c.h4;
            if (tid < 800)
                h8[tid] = __hip_atomic_load(hq8 + tid, __ATOMIC_RELAXED,
                                            __HIP_MEMORY_SCOPE_AGENT);
            __syncthreads();

            // gi(t+1) prefetch issued early: L2 latency hides under the GEMV
            if (is_fin && t + 1 < Lsz) {
                const float* gp = gi + ((size_t)(t + 1) * H3 + fd) * 64
                                + (bg * 4 + fbq);
                g2r = gp[0];
                g2z = gp[(size_t)Hsz * 64];
                g2n = gp[(size_t)2 * Hsz * 64];
            }

            // GEMV partials: 900 threads (14 waves), 3 gate-rows x 2 batches
            // per thread over a ~5.6-k4 slice. 5 LDS reads per 24 FMA.
            if (tid < 900) {
                const float4* Wr = sm.c.W4 + (0 * 25 + gdd) * 101;
                const float4* Wz = sm.c.W4 + (1 * 25 + gdd) * 101;
                const float4* Wn = sm.c.W4 + (2 * 25 + gdd) * 101;
                float4 ar0 = make_float4(0.f, 0.f, 0.f, 0.f), ar1 = ar0;
                float4 az0 = ar0, az1 = ar0, an0 = ar0, an1 = ar0;
                for (int k4 = gk4b; k4 < gk4e; ++k4) {
                    float4 h0 = sm.c.h4[(k4 << 2) | gbq0];
                    float4 h1 = sm.c.h4[(k4 << 2) | gbq0 | 1];
                    float4 wr = Wr[k4], wz = Wz[k4], wn = Wn[k4];
                    ar0.x = fmaf(wr.x, h0.x, ar0.x); ar0.y = fmaf(wr.y, h0.y, ar0.y);
                    ar0.z = fmaf(wr.z, h0.z, ar0.z); ar0.w = fmaf(wr.w, h0.w, ar0.w);
                    ar1.x = fmaf(wr.x, h1.x, ar1.x); ar1.y = fmaf(wr.y, h1.y, ar1.y);
                    ar1.z = fmaf(wr.z, h1.z, ar1.z); ar1.w = fmaf(wr.w, h1.w, ar1.w);
                    az0.x = fmaf(wz.x, h0.x, az0.x); az0.y = fmaf(wz.y, h0.y, az0.y);
                    az0.z = fmaf(wz.z, h0.z, az0.z); az0.w = fmaf(wz.w, h0.w, az0.w);
                    az1.x = fmaf(wz.x, h1.x, az1.x); az1.y = fmaf(wz.y, h1.y, az1.y);
                    az1.z = fmaf(wz.z, h1.z, az1.z); az1.w = fmaf(wz.w, h1.w, az1.w);
                    an0.x = fmaf(wn.x, h0.x, an0.x); an0.y = fmaf(wn.y, h0.y, an0.y);
                    an0.z = fmaf(wn.z, h0.z, an0.z); an0.w = fmaf(wn.w, h0.w, an0.w);
                    an1.x = fmaf(wn.x, h1.x, an1.x); an1.y = fmaf(wn.y, h1.y, an1.y);
                    an1.z = fmaf(wn.z, h1.z, an1.z); an1.w = fmaf(wn.w, h1.w, an1.w);
                }
                sm.c.part[PIDX(gks, 0, gdd, gbq0)]     = (ar0.x + ar0.y) + (ar0.z + ar0.w);
                sm.c.part[PIDX(gks, 0, gdd, gbq0 | 1)] = (ar1.x + ar1.y) + (ar1.z + ar1.w);
                sm.c.part[PIDX(gks, 1, gdd, gbq0)]     = (az0.x + az0.y) + (az0.z + az0.w);
                sm.c.part[PIDX(gks, 1, gdd, gbq0 | 1)] = (az1.x + az1.y) + (az1.z + az1.w);
                sm.c.part[PIDX(gks, 2, gdd, gbq0)]     = (an0.x + an0.y) + (an0.z + an0.w);
                sm.c.part[PIDX(gks, 2, gdd, gbq0 | 1)] = (an1.x + an1.y) + (an1.z + an1.w);
            }
            __syncthreads();

            // finalize: waves 0+1, one (dd,bq) unit per thread, sum 18 k-splits
            if (is_fin) {
                float ghr = bhr, ghz = bhz, ghn = bhn;
                #pragma unroll
                for (int ks = 0; ks < KS; ++ks) {
                    ghr += sm.c.part[PIDX(ks, 0, fdd, fbq)];
                    ghz += sm.c.part[PIDX(ks, 1, fdd, fbq)];
                    ghn += sm.c.part[PIDX(ks, 2, fdd, fbq)];
                }
                float rr = sigmoidf_(g1r + bir + ghr);
                float zz = sigmoidf_(g1z + biz + ghz);
                float nn = tanhf(g1n + bin + rr * ghn);
                int hidx = (((fd >> 2) << 2) | fbq) * 4 + (fd & 3);
                float hp = ((const float*)sm.c.h4)[hidx];
                float hv = (1.f - zz) * nn + zz * hp;
                // device-visible (IF) store: peers read via bypass loads
                __hip_atomic_store(&hq_nxt[hidx], hv, __ATOMIC_RELAXED,
                                   __HIP_MEMORY_SCOPE_AGENT);
                h_all[(size_t)(bg * 4 + fbq) * (Lsz * Hsz)
                      + (size_t)t * Hsz + fd] = hv;
                g1r = g2r; g1z = g2z; g1n = g2n;
            }

            if (t < Lsz - 1) {
                __syncthreads();
                // one release-add per finalize wave: each wave's release drains
                // its OWN h stores (vmcnt is per-wave) before publishing at IF
                if (tid == 0 || tid == 64) {
                    __hip_atomic_fetch_add(ctr, 1u, __ATOMIC_RELEASE,
                                           __HIP_MEMORY_SCOPE_AGENT);
                }
                if (tid == 0) {
                    unsigned target = 2u * (unsigned)DGRP * (t + 1);
                    while (__hip_atomic_load(ctr, __ATOMIC_RELAXED,
                                             __HIP_MEMORY_SCOPE_AGENT) < target) {
                        __builtin_amdgcn_s_sleep(1);
                    }
                }
                __syncthreads();
            }
        }
        return;
    }

    // ================= tf==0 fallback: per-batch independent decode =========
    if (blockIdx.x >= Bsz) return;
    const int b    = blockIdx.x;
    const int lane = tid & 63;
    const int w    = tid >> 6;          // 0..14
    const int jc   = tid % 300;
    const int ksf  = tid / 300;
    const int kbeg = ksf * 134;
    const int kend = (ksf == 2) ? Hsz : kbeg + 134;
    const int len  = lens[b];

    const float4* WTH4 = (const float4*)(ws_ro + WT_HH_OFF);
    const float4* WTI4 = (const float4*)(ws_ro + WT_IH_OFF);

    if (tid < Hsz) {
        sm.f.hx[tid] = enc_hidden[b * Hsz + tid];
        sm.f.xv[tid] = slot_emb[(size_t)slot_p[0] * Dsz + tid];
    }
    __syncthreads();

    for (int t = 0; t < Lsz; ++t) {
        if (tid < 900) {
            float4 ai = make_float4(0.f, 0.f, 0.f, 0.f);
            float4 ah = make_float4(0.f, 0.f, 0.f, 0.f);
            for (int k = kbeg; k < kend; ++k) {
                float4 wi = WTI4[(size_t)k * 300 + jc];
                float4 wh = WTH4[(size_t)k * 300 + jc];
                float x = sm.f.xv[k], h = sm.f.hx[k];
                ai.x = fmaf(wi.x, x, ai.x); ai.y = fmaf(wi.y, x, ai.y);
                ai.z = fmaf(wi.z, x, ai.z); ai.w = fmaf(wi.w, x, ai.w);
                ah.x = fmaf(wh.x, h, ah.x); ah.y = fmaf(wh.y, h, ah.y);
                ah.z = fmaf(wh.z, h, ah.z); ah.w = fmaf(wh.w, h, ah.w);
            }
            ((float4*)sm.f.part_i)[ksf * 300 + jc] = ai;
            ((float4*)sm.f.part_h)[ksf * 300 + jc] = ah;
        }
        __syncthreads();

        if (tid < Hsz) {
            int d = tid;
            float i_r = sm.f.part_i[d]           + sm.f.part_i[H3 + d]           + sm.f.part_i[2 * H3 + d]           + b_ih[d];
            float i_z = sm.f.part_i[d + Hsz]     + sm.f.part_i[H3 + d + Hsz]     + sm.f.part_i[2 * H3 + d + Hsz]     + b_ih[d + Hsz];
            float i_n = sm.f.part_i[d + 2 * Hsz] + sm.f.part_i[H3 + d + 2 * Hsz] + sm.f.part_i[2 * H3 + d + 2 * Hsz] + b_ih[d + 2 * Hsz];
            float h_r = sm.f.part_h[d]           + sm.f.part_h[H3 + d]           + sm.f.part_h[2 * H3 + d]           + b_hh[d];
            float h_z = sm.f.part_h[d + Hsz]     + sm.f.part_h[H3 + d + Hsz]     + sm.f.part_h[2 * H3 + d + Hsz]     + b_hh[d + Hsz];
            float h_n = sm.f.part_h[d + 2 * Hsz] + sm.f.part_h[H3 + d + 2 * Hsz] + sm.f.part_h[2 * H3 + d + 2 * Hsz] + b_hh[d + 2 * Hsz];
            float r = sigmoidf_(i_r + h_r);
            float z = sigmoidf_(i_z + h_z);
            float n = tanhf(i_n + r * h_n);
            sm.f.hx[d] = (1.f - z) * n + z * sm.f.hx[d];
        }
        __syncthreads();

        const float4* hx4 = (const float4*)sm.f.hx;
        for (int s = w; s < len; s += 15) {
            const float4* e4 = (const float4*)(enc_out + ((size_t)b * Ssz + s) * Hsz);
            float4 ev = e4[lane];
            float4 hv = hx4[lane];
            float acc = ev.x * hv.x + ev.y * hv.y + ev.z * hv.z + ev.w * hv.w;
            if (lane < 36) {
                float4 ev2 = e4[64 + lane];
                float4 hv2 = hx4[64 + lane];
                acc += ev2.x * hv2.x + ev2.y * hv2.y + ev2.z * hv2.z + ev2.w * hv2.w;
            }
            #pragma unroll
            for (int off = 32; off >= 1; off >>= 1) acc += __shfl_xor(acc, off, 64);
            if (lane == 0) sm.f.sL[s] = acc;
        }
        __syncthreads();

        float bv = -INFINITY; int bi = 0x7fffffff;
        for (int s = tid; s < len; s += 960) {
            float v = sm.f.sL[s];
            if (v > bv || (v == bv && s < bi)) { bv = v; bi = s; }
        }
        #pragma unroll
        for (int off = 32; off >= 1; off >>= 1) {
            float ov = __shfl_xor(bv, off, 64);
            int   oi = __shfl_xor(bi, off, 64);
            if (ov > bv || (ov == bv && oi < bi)) { bv = ov; bi = oi; }
        }
        if (lane == 0) { sm.f.redv[w] = bv; sm.f.redi[w] = bi; }
        __syncthreads();
        if (tid == 0) {
            float mv = sm.f.redv[0]; int mi = sm.f.redi[0];
            for (int i = 1; i < 15; ++i)
                if (sm.f.redv[i] > mv || (sm.f.redv[i] == mv && sm.f.redi[i] < mi)) {
                    mv = sm.f.redv[i]; mi = sm.f.redi[i];
                }
            sm.f.bc_max = mv; sm.f.bc_idx = mi;
        }
        __syncthreads();
        float maxv = sm.f.bc_max;
        int   amax = sm.f.bc_idx;

        float ls = 0.f;
        for (int s = tid; s < len; s += 960) {
            float e = expf(sm.f.sL[s] - maxv);
            sm.f.sL[s] = e;
            ls += e;
        }
        #pragma unroll
        for (int off = 32; off >= 1; off >>= 1) ls += __shfl_xor(ls, off, 64);
        if (lane == 0) sm.f.redv[w] = ls;
        __syncthreads();
        if (tid == 0) {
            float sms = 0.f;
            for (int i = 0; i < 15; ++i) sms += sm.f.redv[i];
            sm.f.bc_sum = sms;
        }
        __syncthreads();
        float sum = sm.f.bc_sum;

        float* orow = out_probs + (size_t)b * (Lsz * Vsz) + (size_t)t * Vsz;
        for (int s = tid; s < len; s += 960) {
            atomicAdd(&orow[uttrs[b * Ssz + s]], sm.f.sL[s] / sum);
        }

        int predtok = uttrs[b * Ssz + amax];
        if (tid == 0) preds_out[(size_t)t * Bsz + b] = (float)predtok;
        __syncthreads();
        if (tid < Dsz) sm.f.xv[tid] = embedding[(size_t)predtok * Dsz + tid];
        __syncthreads();
    }
}

// ---------------------------------------------------------------------------
// Batched scores (tf==1): scores[t][b][s] = h_t[b].enc_out[b][s], s < len[b].
// ---------------------------------------------------------------------------
__global__ __launch_bounds__(256) void k_scores(const float* __restrict__ h_all,
                                                const float* __restrict__ enc_out,
                                                const int* __restrict__ lens,
                                                const int* __restrict__ tf_p,
                                                float* __restrict__ scores_all) {
    if (tf_p[0] == 0) return;
    __shared__ float4 hS[Lsz * 100];   // 25.6 KB

    int b  = blockIdx.x >> 3;
    int sc = blockIdx.x & 7;
    int tid = threadIdx.x;
    int lane = tid & 63;
    int w = tid >> 6;

    const float4* h4g = (const float4*)(h_all + (size_t)b * (Lsz * Hsz));
    for (int i = tid; i < Lsz * 100; i += 256) hS[i] = h4g[i];
    __syncthreads();

    int len = lens[b];
    int l2 = 64 + ((lane < 36) ? lane : 0);
    float mult2 = (lane < 36) ? 1.f : 0.f;

    for (int i = 0; i < 16; ++i) {
        int s = sc * 64 + i * 4 + w;
        if (s >= len) continue;
        const float4* e4 = (const float4*)(enc_out + ((size_t)b * Ssz + s) * Hsz);
        float4 ev  = e4[lane];
        float4 ev2 = e4[l2];
        ev2.x *= mult2; ev2.y *= mult2; ev2.z *= mult2; ev2.w *= mult2;

        float acc[Lsz];
        #pragma unroll
        for (int t = 0; t < Lsz; ++t) {
            float4 hv  = hS[t * 100 + lane];
            float4 hv2 = hS[t * 100 + l2];
            float a = ev.x * hv.x + ev.y * hv.y + ev.z * hv.z + ev.w * hv.w;
            a += ev2.x * hv2.x + ev2.y * hv2.y + ev2.z * hv2.z + ev2.w * hv2.w;
            acc[t] = a;
        }
        #pragma unroll
        for (int off = 32; off >= 1; off >>= 1) {
            #pragma unroll
            for (int t = 0; t < Lsz; ++t) acc[t] += __shfl_xor(acc[t], off, 64);
        }
        if (lane == 0) {
            #pragma unroll
            for (int t = 0; t < Lsz; ++t)
                scores_all[(size_t)t * (Bsz * Ssz) + b * Ssz + s] = acc[t];
        }
    }
}

// ---------------------------------------------------------------------------
// Batched softmax + LDS-vocab scatter + argmax (tf==1): one block per (t,b).
// Accumulates pointer dist in 128 KB LDS, streams full row out (no zeroing,
// no global atomics).
// ---------------------------------------------------------------------------
__global__ __launch_bounds__(256) void k_softmax_all(const float* __restrict__ scores_all,
                                                     const int* __restrict__ lens,
                                                     const int* __restrict__ uttrs,
                                                     const int* __restrict__ tf_p,
                                                     float* __restrict__ out_probs,
                                                     float* __restrict__ preds_out) {
    if (tf_p[0] == 0) return;
    __shared__ float4 vb4[Vsz / 4];   // 128 KB vocab accumulator
    __shared__ float sL[Ssz];
    __shared__ float redv[4];
    __shared__ int   redi[4];
    __shared__ float bc_max, bc_sum;
    __shared__ int   bc_idx;

    int t = blockIdx.x >> 6;
    int b = blockIdx.x & 63;
    int tid = threadIdx.x;
    int lane = tid & 63, w = tid >> 6;
    int len = lens[b];
    const float* srow = scores_all + (size_t)t * (Bsz * Ssz) + b * Ssz;

    float4 z4 = make_float4(0.f, 0.f, 0.f, 0.f);
    for (int i = tid; i < Vsz / 4; i += 256) vb4[i] = z4;

    for (int s = tid; s < len; s += 256) sL[s] = srow[s];
    __syncthreads();

    float bv = -INFINITY; int bi = 0x7fffffff;
    for (int s = tid; s < len; s += 256) {
        float v = sL[s];
        if (v > bv || (v == bv && s < bi)) { bv = v; bi = s; }
    }
    #pragma unroll
    for (int off = 32; off >= 1; off >>= 1) {
        float ov = __shfl_xor(bv, off, 64);
        int   oi = __shfl_xor(bi, off, 64);
        if (ov > bv || (ov == bv && oi < bi)) { bv = ov; bi = oi; }
    }
    if (lane == 0) { redv[w] = bv; redi[w] = bi; }
    __syncthreads();
    if (tid == 0) {
        float mv = redv[0]; int mi = redi[0];
        for (int i = 1; i < 4; ++i)
            if (redv[i] > mv || (redv[i] == mv && redi[i] < mi)) { mv = redv[i]; mi = redi[i]; }
        bc_max = mv; bc_idx = mi;
    }
    __syncthreads();
    float maxv = bc_max;
    int   amax = bc_idx;

    float ls = 0.f;
    for (int s = tid; s < len; s += 256) {
        float e = expf(sL[s] - maxv);
        sL[s] = e;
        ls += e;
    }
    #pragma unroll
    for (int off = 32; off >= 1; off >>= 1) ls += __shfl_xor(ls, off, 64);
    if (lane == 0) redv[w] = ls;
    __syncthreads();
    if (tid == 0) bc_sum = redv[0] + redv[1] + redv[2] + redv[3];
    __syncthreads();
    float sum = bc_sum;

    float* vbf = (float*)vb4;
    for (int s = tid; s < len; s += 256) {
        atomicAdd(&vbf[uttrs[b * Ssz + s]], sL[s] / sum);
    }
    __syncthreads();

    // stream the full vocab row out nontemporally (native vector type)
    const nf4* vbn = (const nf4*)vb4;
    nf4* orow4 = (nf4*)(out_probs + (size_t)b * (Lsz * Vsz) + (size_t)t * Vsz);
    for (int i = tid; i < Vsz / 4; i += 256)
        __builtin_nontemporal_store(vbn[i], &orow4[i]);

    if (tid == 0) preds_out[(size_t)t * Bsz + b] = (float)uttrs[b * Ssz + amax];
}

// ---------------------------------------------------------------------------
extern "C" void kernel_launch(void* const* d_in, const int* in_sizes, int n_in,
                              void* d_out, int out_size, void* d_ws, size_t ws_size,
                              hipStream_t stream) {
    const float* enc_hidden = (const float*)d_in[0];
    const float* enc_out    = (const float*)d_in[1];
    const int*   enc_lens   = (const int*)d_in[2];
    const int*   uttrs      = (const int*)d_in[3];
    const int*   tgt        = (const int*)d_in[4];
    const int*   slot_p     = (const int*)d_in[5];
    const int*   tf_p       = (const int*)d_in[6];
    const float* embedding  = (const float*)d_in[7];
    const float* slot_emb   = (const float*)d_in[8];
    const float* W_ih       = (const float*)d_in[9];
    const float* W_hh       = (const float*)d_in[10];
    const float* b_ih       = (const float*)d_in[11];
    const float* b_hh       = (const float*)d_in[12];

    float* out = (float*)d_out;
    float* ws  = (float*)d_ws;

    float* gi_all     = ws + GI_OFF;
    float* h_all      = ws + HALL_OFF;
    float* scores_all = ws + SCALL_OFF;
    float* preds_out  = out + (size_t)Bsz * Lsz * Vsz;

    int n4 = out_size >> 2;

    // 1) init: h0 + barrier ctrs (+ full zero / WT transposes only if tf==0)
    k_init<<<2048, 256, 0, stream>>>(W_hh, W_ih, enc_hidden, tf_p,
                                     (float4*)d_out, n4, ws);

    // 2) gi GEMM for all 16 steps (tf==1 only)
    k_gi<<<256, 256, 0, stream>>>(tgt, slot_p, tf_p, embedding, slot_emb,
                                  W_ih, gi_all);

    // 3) chain (tf==1: 16 independent group-barriers; tf==0: per-batch fallback)
    k_chain<<<NBLK_CHAIN, 960, 0, stream>>>(ws, gi_all, W_hh, enc_hidden, enc_out,
                                            enc_lens, uttrs, slot_p, tf_p,
                                            embedding, slot_emb, b_ih, b_hh,
                                            ws, h_all, out, preds_out);

    // 4) batched scores + softmax/scatter (tf==1 only)
    k_scores<<<512, 256, 0, stream>>>(h_all, enc_out, enc_lens, tf_p, scores_all);
    k_softmax_all<<<1024, 256, 0, stream>>>(scores_all, enc_lens, uttrs, tf_p,
                                            out, preds_out);
}